// Round 19
// baseline (189.738 us; speedup 1.0000x reference)
//
#include <hip/hip_runtime.h>
#include <hip/hip_bf16.h>
#include <stdint.h>

// Problem constants (B,T,C,NH,LEVEL) = (2,2048,1024,16,3)
#define B_    2
#define T_    2048
#define CD    1024
#define NH_   16
#define HS_   64
#define NSETS 511        // sum_{l=3..11} 2048>>l
#define NSP   512        // padded
#define QKV_LD 3072
#define NEGBIG (-3.4e38f)
#define QSC   (0.125f * 1.44269504088896f)   // scale * log2(e): exp2-domain softmax

typedef __attribute__((ext_vector_type(8))) short  short8;
typedef __attribute__((ext_vector_type(4))) float  f32x4;
typedef _Float16 half8v __attribute__((ext_vector_type(8)));

__device__ __forceinline__ unsigned short f2bf(float f) {
  unsigned u = __float_as_uint(f);
  unsigned r = 0x7FFFu + ((u >> 16) & 1u);   // round-to-nearest-even
  return (unsigned short)((u + r) >> 16);
}
__device__ __forceinline__ float bf2f(unsigned short h) {
  return __uint_as_float(((unsigned)h) << 16);
}
__device__ __forceinline__ unsigned short f2h(float v) {
  _Float16 h = (_Float16)v;                  // RTN
  return __builtin_bit_cast(unsigned short, h);
}
__device__ __forceinline__ float elu1(float x) {  // elu(x)+1
  return x > 0.f ? x + 1.f : __expf(x);
}
__device__ __forceinline__ void gload16(const unsigned short* g, short* l) {
  __builtin_amdgcn_global_load_lds(
      (const __attribute__((address_space(1))) unsigned int*)g,
      (__attribute__((address_space(3))) unsigned int*)l, 16, 0, 0);
}

// ---------------- K1: fused splits -----------------------------------------
__global__ __launch_bounds__(256) void split3_kernel(
    const float* __restrict__ x, const float* __restrict__ Wa,
    const float* __restrict__ Wp,
    unsigned short* __restrict__ xh, unsigned short* __restrict__ xl,
    unsigned short* __restrict__ xf,
    unsigned short* __restrict__ waqh, unsigned short* __restrict__ waql,
    unsigned short* __restrict__ wakvf, unsigned short* __restrict__ wph) {
  int bid = blockIdx.x;
  int t = threadIdx.x;
  if (bid < 16384) {                     // x: 4096x1024
    int i = bid * 256 + t;
    float v = x[i];
    unsigned short h = f2bf(v);
    xh[i] = h;
    xl[i] = f2bf(v - bf2f(h));
    xf[i] = f2h(v);
  } else if (bid < 20480) {              // Wa rows 0..1023 (q)
    int i = (bid - 16384) * 256 + t;
    float v = Wa[i];
    unsigned short h = f2bf(v);
    waqh[i] = h;
    waql[i] = f2bf(v - bf2f(h));
  } else if (bid < 28672) {              // Wa rows 1024..3071 (k,v)
    int i = (bid - 20480) * 256 + t;
    wakvf[i] = f2h(Wa[1048576 + i]);
  } else {                               // Wp
    int i = (bid - 28672) * 256 + t;
    wph[i] = f2bf(Wp[i]);
  }
}

// ---------------- GEMM body: C[128 x BN tile] = A*B^T (MFMA) ---------------
template<int SPLIT, int BN, int F16>
__device__ __forceinline__ void gemm_body(
    short* lds,
    const unsigned short* __restrict__ Ah, const unsigned short* __restrict__ Al,
    const unsigned short* __restrict__ Bh, const unsigned short* __restrict__ Bl,
    float* __restrict__ Cmat, int K, int ldc, int row0, int col0)
{
  constexpr int NB   = BN / 16;
  constexpr int ALD  = 8 * (1 + SPLIT);
  constexpr int TL   = ALD + NB * (1 + SPLIT);
  constexpr int PW   = TL / 4;
  constexpr int ASH  = (1 + SPLIT) * 4096;
  constexpr int ABYT = ASH * 2;
  constexpr int NC   = BN / 32;

  const int tid  = threadIdx.x;
  const int lane = tid & 63;
  const int w    = tid >> 6;
  const int wr   = w >> 1, wc = w & 1;

  f32x4 acc[4][NC];
  #pragma unroll
  for (int a = 0; a < 4; ++a)
    #pragma unroll
    for (int b = 0; b < NC; ++b)
      acc[a][b] = (f32x4){0.f, 0.f, 0.f, 0.f};

  const int rlane = lane & 15;
  const int kgrp  = lane >> 4;
  const int rsw   = (kgrp ^ (rlane & 3) ^ ((rlane >> 2) & 3)) << 4;

  const int slr = lane >> 2;
  const int sch = (lane & 3) ^ (slr & 3) ^ ((slr >> 2) & 3);

  for (int kt = 0; kt < K; kt += 32) {
    __syncthreads();
    #pragma unroll
    for (int li = 0; li < PW; ++li) {
      int L = w * PW + li;
      const unsigned short* src; int dsts; size_t rowb;
      if (L < 8)                { src = Ah; rowb = (size_t)row0 + L * 16;       dsts = L * 512; }
      else if (SPLIT && L < 16) { src = Al; rowb = (size_t)row0 + (L - 8) * 16; dsts = 4096 + (L - 8) * 512; }
      else {
        int Lb = L - ALD;
        if (!SPLIT || Lb < NB) { src = Bh; rowb = (size_t)col0 + Lb * 16;        dsts = ASH + Lb * 512; }
        else                   { src = Bl; rowb = (size_t)col0 + (Lb - NB) * 16; dsts = ASH + BN * 32 + (Lb - NB) * 512; }
      }
      gload16(src + (rowb + slr) * K + kt + (sch << 3), lds + dsts + lane * 8);
    }
    __syncthreads();

    short8 aH[4], bH[NC], aL[4], bL[NC];
    #pragma unroll
    for (int m = 0; m < 4; ++m) {
      int r = wr * 64 + m * 16 + rlane;
      aH[m] = *(const short8*)((const char*)lds + r * 64 + rsw);
      if (SPLIT) aL[m] = *(const short8*)((const char*)lds + 8192 + r * 64 + rsw);
    }
    #pragma unroll
    for (int n = 0; n < NC; ++n) {
      int c = wc * (BN / 2) + n * 16 + rlane;
      bH[n] = *(const short8*)((const char*)lds + ABYT + c * 64 + rsw);
      if (SPLIT) bL[n] = *(const short8*)((const char*)lds + ABYT + BN * 64 + c * 64 + rsw);
    }
    #pragma unroll
    for (int mm = 0; mm < 4; ++mm)
      #pragma unroll
      for (int nn = 0; nn < NC; ++nn) {
        if (F16) {
          acc[mm][nn] = __builtin_amdgcn_mfma_f32_16x16x32_f16(
              __builtin_bit_cast(half8v, aH[mm]), __builtin_bit_cast(half8v, bH[nn]),
              acc[mm][nn], 0, 0, 0);
        } else {
          acc[mm][nn] = __builtin_amdgcn_mfma_f32_16x16x32_bf16(aH[mm], bH[nn], acc[mm][nn], 0, 0, 0);
          if (SPLIT) {
            acc[mm][nn] = __builtin_amdgcn_mfma_f32_16x16x32_bf16(aH[mm], bL[nn], acc[mm][nn], 0, 0, 0);
            acc[mm][nn] = __builtin_amdgcn_mfma_f32_16x16x32_bf16(aL[mm], bH[nn], acc[mm][nn], 0, 0, 0);
          }
        }
      }
  }

  const int rl = (lane >> 4) * 4;
  const int cl = lane & 15;
  #pragma unroll
  for (int mm = 0; mm < 4; ++mm)
    #pragma unroll
    for (int nn = 0; nn < NC; ++nn)
      #pragma unroll
      for (int r = 0; r < 4; ++r) {
        int row = row0 + wr * 64 + mm * 16 + rl + r;
        int col = col0 + wc * (BN / 2) + nn * 16 + cl;
        Cmat[(size_t)row * ldc + col] = acc[mm][nn][r];
      }
}

// ---------------- K2/K7: standalone GEMM with XCD swizzle ------------------
template<int SPLIT, int BN, int F16>
__global__ __launch_bounds__(256) void gemm_bt(
    const unsigned short* __restrict__ Ah, const unsigned short* __restrict__ Al,
    const unsigned short* __restrict__ Bh, const unsigned short* __restrict__ Bl,
    float* __restrict__ Cmat, int M, int N, int K, int ldc)
{
  __shared__ short lds[(1 + SPLIT) * 4096 + (1 + SPLIT) * BN * 32];
  const int nwg = gridDim.x;
  const int cpx = nwg >> 3;
  const int bid = blockIdx.x;
  const int swb = (bid & 7) * cpx + (bid >> 3);
  const int nbx = N / BN;
  const int bx = swb % nbx;
  const int by = swb / nbx;
  gemm_body<SPLIT, BN, F16>(lds, Ah, Al, Bh, Bl, Cmat, K, ldc, by * 128, bx * BN);
}

// ---------------- K3a: per-seg partial sums (16-row segments) --------------
__global__ __launch_bounds__(256) void cs_part(const float* __restrict__ qkv,
                                               float* __restrict__ part) {
  int blk = blockIdx.x;                 // B*128*2 = 512
  int q   = blk & 1;
  int seg = (blk >> 1) & 127;
  int b   = blk >> 8;
  int c   = threadIdx.x * 4;            // 0..1023
  const float* src = qkv + (size_t)(b * T_ + seg * 16) * QKV_LD + CD + q * CD + c;
  float4 s = {0.f, 0.f, 0.f, 0.f};
  #pragma unroll 4
  for (int j = 0; j < 16; ++j) {
    float4 v = *(const float4*)(src + (size_t)j * QKV_LD);
    if (q == 0) {
      s.x += elu1(v.x); s.y += elu1(v.y); s.z += elu1(v.z); s.w += elu1(v.w);
    } else {
      s.x += v.x; s.y += v.y; s.z += v.z; s.w += v.w;
    }
  }
  *(float4*)(part + ((size_t)(b * 128 + seg) * 2048) + q * 1024 + c) = s;
}

// ---------------- K3b: final walk with self-prefix -> kcum / vcum ---------
__global__ __launch_bounds__(256) void cs_final(const float* __restrict__ qkv,
                                                const float* __restrict__ part,
                                                float* __restrict__ kcum,
                                                float* __restrict__ vcum) {
  int blk = blockIdx.x;                 // 512
  int q   = blk & 1;
  int seg = (blk >> 1) & 127;
  int b   = blk >> 8;
  int c   = threadIdx.x * 4;
  int h   = c >> 6, d = c & 63;
  float4 s = {0.f, 0.f, 0.f, 0.f};
  const float* pb = part + (size_t)(b * 128) * 2048 + q * 1024 + c;
  #pragma unroll 8
  for (int ss = 0; ss < seg; ++ss) {
    float4 p = *(const float4*)(pb + (size_t)ss * 2048);
    s.x += p.x; s.y += p.y; s.z += p.z; s.w += p.w;
  }
  const float* src = qkv + (size_t)(b * T_ + seg * 16) * QKV_LD + CD + q * CD + c;
  float* dst = (q == 0 ? kcum : vcum) + ((size_t)(b * NH_ + h) * T_ + seg * 16) * HS_ + d;
  #pragma unroll 4
  for (int j = 0; j < 16; ++j) {
    float4 v = *(const float4*)(src + (size_t)j * QKV_LD);
    if (q == 0) {
      s.x += elu1(v.x); s.y += elu1(v.y); s.z += elu1(v.z); s.w += elu1(v.w);
    } else {
      s.x += v.x; s.y += v.y; s.z += v.z; s.w += v.w;
    }
    *(float4*)(dst + (size_t)j * HS_) = s;
  }
}

// ---------------- K4: sorted set aggregates + fused V transpose ------------
__global__ __launch_bounds__(256) void build_sets2(
    const float* __restrict__ kcum, const float* __restrict__ vcum,
    unsigned short* __restrict__ Ksh, unsigned short* __restrict__ Ksl,
    unsigned short* __restrict__ Vst, int* __restrict__ r_srt)
{
  __shared__ int   lr[64], lli[64];
  __shared__ float vt[64][65];
  const int bh = blockIdx.x >> 3;
  const int s0 = (blockIdx.x & 7) * 64;
  const int tid = threadIdx.x;

  for (int s = tid; s < NSP; s += 256) {
    int r, li, rank;
    if (s == NSETS) { r = 0x7fffffff; li = 0; rank = NSETS; }
    else {
      int lvl = 3, base = 0;
      while (s >= base + (T_ >> lvl)) { base += T_ >> lvl; ++lvl; }
      int i = s - base;
      int m = (i + 1) << lvl;
      r = m - 1; li = i << lvl;
      rank = lvl - 3;
      #pragma unroll
      for (int j = 3; j <= 11; ++j) rank += (m - 8) >> j;
    }
    if (rank >= s0 && rank < s0 + 64) {
      lr[rank - s0]  = r;
      lli[rank - s0] = li;
      if (bh == 0) r_srt[rank] = r;
    }
  }
  __syncthreads();

  const int sl = tid >> 2;          // local rank
  const int dq = (tid & 3) * 16;
  const int r  = lr[sl], li = lli[sl];
  const size_t orow = ((size_t)(bh << 9) + s0 + sl) * HS_ + dq;
  short8 kh0, kh1, kl0, kl1;
  if (r == 0x7fffffff) {
    #pragma unroll
    for (int j = 0; j < 8; ++j) { kh0[j]=0; kh1[j]=0; kl0[j]=0; kl1[j]=0; }
    #pragma unroll
    for (int j = 0; j < 16; ++j) vt[sl][dq + j] = 0.f;
  } else {
    const float* kr0 = kcum + ((size_t)bh * T_ + r) * HS_ + dq;
    const float* vr0 = vcum + ((size_t)bh * T_ + r) * HS_ + dq;
    const float* kr1 = kcum + ((size_t)bh * T_ + (li - 1)) * HS_ + dq;
    const float* vr1 = vcum + ((size_t)bh * T_ + (li - 1)) * HS_ + dq;
    #pragma unroll
    for (int g = 0; g < 4; ++g) {
      float4 kv = *(const float4*)(kr0 + g * 4);
      float4 vv = *(const float4*)(vr0 + g * 4);
      if (li > 0) {
        float4 k1 = *(const float4*)(kr1 + g * 4);
        float4 v1 = *(const float4*)(vr1 + g * 4);
        kv.x -= k1.x; kv.y -= k1.y; kv.z -= k1.z; kv.w -= k1.w;
        vv.x -= v1.x; vv.y -= v1.y; vv.z -= v1.z; vv.w -= v1.w;
      }
      float ka[4] = {kv.x, kv.y, kv.z, kv.w};
      float va[4] = {vv.x, vv.y, vv.z, vv.w};
      #pragma unroll
      for (int j = 0; j < 4; ++j) {
        int e = g * 4 + j;
        unsigned short h = f2bf(ka[j]);
        unsigned short l = f2bf(ka[j] - bf2f(h));
        if (e < 8) { kh0[e] = (short)h; kl0[e] = (short)l; }
        else       { kh1[e - 8] = (short)h; kl1[e - 8] = (short)l; }
        vt[sl][dq + e] = va[j];
      }
    }
  }
  *(short8*)(Ksh + orow)     = kh0;
  *(short8*)(Ksh + orow + 8) = kh1;
  *(short8*)(Ksl + orow)     = kl0;
  *(short8*)(Ksl + orow + 8) = kl1;
  __syncthreads();

  const int d  = tid >> 2;
  const int sq = (tid & 3) * 16;
  short8 a, b2;
  #pragma unroll
  for (int j = 0; j < 8; ++j) {
    a[j]  = (short)f2bf(vt[sq + j][d]);
    b2[j] = (short)f2bf(vt[sq + 8 + j][d]);
  }
  unsigned short* dst = Vst + ((size_t)(bh << 6) + d) * NSP + s0 + sq;
  *(short8*)dst = a;
  *(short8*)(dst + 8) = b2;
}

// ---------------- K5: MFMA flash attention, set-split + LDS-trimmed --------
// 1536 blocks (tch<16: 1 block; tch>=16: 2 set-range blocks w/ partials).
// With the P-alias trim (26.6KB LDS, 84 VGPR) ALL 6 blocks/CU co-resident:
// 24 waves/CU latency hiding, each block <=4(+1) tiles.
__global__ __launch_bounds__(256) void attn_mfma(
    const float* __restrict__ qkv, const float* __restrict__ kcum,
    const float* __restrict__ vcum,
    const unsigned short* __restrict__ Ksh, const unsigned short* __restrict__ Ksl,
    const unsigned short* __restrict__ Vst, const int* __restrict__ r_srt,
    unsigned short* __restrict__ attnb,
    unsigned short* __restrict__ pO, float* __restrict__ pm, float* __restrict__ pl)
{
  __shared__ short KV[3 * 4096];        // 24KB; Ksh region doubles as P buffer
  __shared__ int   rs_lds[NSP];         // 2KB

  const int blk = blockIdx.x;           // 1536
  const int xcd = blk & 7;
  const int j   = blk >> 3;             // 0..191
  const int bh  = xcd * 4 + j / 48;
  const int idx = j % 48;
  int tch, grp, ngrp;
  if (idx < 16) { tch = idx; grp = 0; ngrp = 1; }
  else { int e = idx - 16; tch = 16 + (e >> 1); grp = e & 1; ngrp = 2; }

  const int b = bh >> 4, h = bh & 15;
  const int t0 = tch * 64;
  const int tid = threadIdx.x;
  const int lane = tid & 63;
  const int w = tid >> 6;
  const int col = lane & 15;
  const int kgrp = (lane >> 4) * 8;

  const int srow = lane >> 3;
  const int scsw = ((lane & 7) ^ srow) * 8;

  auto stage_tile = [&](int s0) {
    #pragma unroll
    for (int L = w * 6; L < w * 6 + 6; ++L) {
      int a = L >> 3, i = L & 7;
      const unsigned short* src;
      if (a == 0)      src = Ksh + ((size_t)(bh << 9) + s0 + i * 8 + srow) * 64 + scsw;
      else if (a == 1) src = Ksl + ((size_t)(bh << 9) + s0 + i * 8 + srow) * 64 + scsw;
      else             src = Vst + ((size_t)(bh << 6) + i * 8 + srow) * NSP + s0 + scsw;
      gload16(src, KV + a * 4096 + i * 512 + lane * 8);
    }
  };

  // ---- Q fragments: global -> pre-scaled split bf16 hi/lo in registers ----
  short8 qh[2], ql[2];
  {
    int qrow = t0 + w * 16 + col;
    const float* qr = qkv + (size_t)(b * T_ + qrow) * QKV_LD + h * HS_;
    #pragma unroll
    for (int ks = 0; ks < 2; ++ks) {
      float4 v0 = *(const float4*)(qr + kgrp + ks * 32);
      float4 v1 = *(const float4*)(qr + kgrp + ks * 32 + 4);
      float vv[8] = {v0.x, v0.y, v0.z, v0.w, v1.x, v1.y, v1.z, v1.w};
      #pragma unroll
      for (int jj = 0; jj < 8; ++jj) {
        float sv = vv[jj] * QSC;
        unsigned short hi = f2bf(sv);
        qh[ks][jj] = (short)hi;
        ql[ks][jj] = (short)f2bf(sv - bf2f(hi));
      }
    }
  }
  for (int s = tid; s < NSP; s += 256) rs_lds[s] = r_srt[s];

  int rows[4];
  #pragma unroll
  for (int r = 0; r < 4; ++r) rows[r] = t0 + w * 16 + (lane >> 4) * 4 + r;

  f32x4 O[4];
  float mrun[4], lsum[4];
  #pragma unroll
  for (int f = 0; f < 4; ++f) {
    O[f] = (f32x4){0.f, 0.f, 0.f, 0.f};
    mrun[f] = NEGBIG; lsum[f] = 0.f;
  }

  int nmax = 0;
  #pragma unroll
  for (int jj = 3; jj <= 11; ++jj) nmax += (t0 + 64) >> jj;
  const int ntiles = (nmax + 63) >> 6;
  const int half   = (ntiles + 1) >> 1;
  const int tstart = (grp == 0) ? 0 : half;
  const int tend   = (ngrp == 2 && grp == 0) ? half : ntiles;

  for (int tile = tstart; tile < tend; ++tile) {
    const int s0 = tile * 64;
    stage_tile(s0);
    __syncthreads();     // drains gload vmcnt(0); covers Q/rs phase on tile 0

    const char* kc = (const char*)KV;
    f32x4 S[4];
    #pragma unroll
    for (int f = 0; f < 4; ++f) S[f] = (f32x4){0.f, 0.f, 0.f, 0.f};

    __builtin_amdgcn_s_setprio(1);
    #pragma unroll
    for (int ks = 0; ks < 2; ++ks) {
      int chnk = (lane >> 4) + ks * 4;
      #pragma unroll
      for (int f = 0; f < 4; ++f) {
        int so = f * 16 + col;
        int kb = so * 128 + ((chnk ^ (so & 7)) << 4);
        short8 bHv = *(const short8*)(kc + kb);
        short8 bLv = *(const short8*)(kc + 8192 + kb);
        S[f] = __builtin_amdgcn_mfma_f32_16x16x32_bf16(qh[ks], bHv, S[f], 0, 0, 0);
        S[f] = __builtin_amdgcn_mfma_f32_16x16x32_bf16(qh[ks], bLv, S[f], 0, 0, 0);
        S[f] = __builtin_amdgcn_mfma_f32_16x16x32_bf16(ql[ks], bHv, S[f], 0, 0, 0);
      }
    }
    __builtin_amdgcn_s_setprio(0);

    int rsv[4];
    #pragma unroll
    for (int f = 0; f < 4; ++f) rsv[f] = rs_lds[s0 + f * 16 + col];

    // logits already in exp2 domain; mask to NEGBIG (exp2 underflows -> 0)
    float zv[4][4];
    #pragma unroll
    for (int f = 0; f < 4; ++f)
      #pragma unroll
      for (int r = 0; r < 4; ++r)
        zv[f][r] = (rsv[f] > rows[r]) ? NEGBIG : S[f][r];

    float mx[4];
    #pragma unroll
    for (int r = 0; r < 4; ++r)
      mx[r] = fmaxf(fmaxf(zv[0][r], zv[1][r]), fmaxf(zv[2][r], zv[3][r]));
    int pred = (mx[0] <= mrun[0] + 11.5f) & (mx[1] <= mrun[1] + 11.5f) &
               (mx[2] <= mrun[2] + 11.5f) & (mx[3] <= mrun[3] + 11.5f);
    if (!__all(pred)) {
      #pragma unroll
      for (int r = 0; r < 4; ++r) {
        float mt = mx[r];
        mt = fmaxf(mt, __shfl_xor(mt, 1));
        mt = fmaxf(mt, __shfl_xor(mt, 2));
        mt = fmaxf(mt, __shfl_xor(mt, 4));
        mt = fmaxf(mt, __shfl_xor(mt, 8));
        float mv = fmaxf(mrun[r], mt);
        float fs = exp2f(mrun[r] - mv);
        lsum[r] *= fs;
        #pragma unroll
        for (int f = 0; f < 4; ++f) O[f][r] *= fs;
        mrun[r] = mv;
      }
    }

    __syncthreads();     // all waves done reading Ksh/Ksl; P may now overwrite

    // ---- P -> bf16 into the (dead) Ksh region, wave-private 2KB slice ----
    char* pw = (char*)KV + w * 2048;
    #pragma unroll
    for (int r = 0; r < 4; ++r) {
      int rowr = (lane >> 4) * 4 + r;
      int rswz = (rowr & 7) << 4;
      #pragma unroll
      for (int f = 0; f < 4; ++f) {
        // masked entries: exp2(NEGBIG - m) == 0. Rows with mrun==NEGBIG
        // accumulate p==1 junk; the tail rescale fs=0 (own block or via
        // combine weight exp2(NEGBIG - m)=0) provably wipes it.
        float p = exp2f(zv[f][r] - mrun[r]);
        lsum[r] += p;
        int addr = (rowr * 128 + (f * 16 + col) * 2) ^ rswz;
        *(unsigned short*)(pw + addr) = f2bf(p);
      }
    }

    __builtin_amdgcn_s_setprio(1);
    #pragma unroll
    for (int ks = 0; ks < 2; ++ks) {
      int chnk = (lane >> 4) + ks * 4;
      int pbyte = (col * 128 + (kgrp + ks * 32) * 2) ^ ((col & 7) << 4);
      short8 pa = *(const short8*)(pw + pbyte);
      #pragma unroll
      for (int f = 0; f < 4; ++f) {
        int dr = f * 16 + col;
        short8 bv = *(const short8*)(kc + 16384 + dr * 128 + ((chnk ^ (dr & 7)) << 4));
        O[f] = __builtin_amdgcn_mfma_f32_16x16x32_bf16(pa, bv, O[f], 0, 0, 0);
      }
    }
    __builtin_amdgcn_s_setprio(0);

    __syncthreads();     // all waves done reading KV/P before next stage
  }

  float lrun[4];
  #pragma unroll
  for (int r = 0; r < 4; ++r) {
    float l = lsum[r];
    l += __shfl_xor(l, 1);
    l += __shfl_xor(l, 2);
    l += __shfl_xor(l, 4);
    l += __shfl_xor(l, 8);
    lrun[r] = l;
  }

  // ---- tail term (only the group containing the last tiles) ----
  if (grp == ngrp - 1) {
    float ztail;
    {
      int trow = lane >> 2;
      int t = t0 + w * 16 + trow;
      int d0 = (lane & 3) * 16;
      const float* qr = qkv + (size_t)(b * T_ + t) * QKV_LD + h * HS_ + d0;
      float qv[16];
      #pragma unroll
      for (int jj = 0; jj < 4; ++jj) {
        float4 v = *(const float4*)(qr + jj * 4);
        qv[jj*4+0] = v.x; qv[jj*4+1] = v.y; qv[jj*4+2] = v.z; qv[jj*4+3] = v.w;
      }
      int lt = t & ~7;
      const float* kc1 = kcum + ((size_t)bh * T_ + t) * HS_ + d0;
      float kt[16];
      if (lt > 0) {
        const float* kc0 = kcum + ((size_t)bh * T_ + (lt - 1)) * HS_ + d0;
        #pragma unroll
        for (int jj = 0; jj < 16; ++jj) kt[jj] = kc1[jj] - kc0[jj];
      } else {
        #pragma unroll
        for (int jj = 0; jj < 16; ++jj) kt[jj] = kc1[jj];
      }
      float z = 0.f;
      #pragma unroll
      for (int jj = 0; jj < 16; ++jj) {
        float qp = qv[jj] > 0.f ? qv[jj] + 1.f : __expf(qv[jj]);
        z += qp * kt[jj];
      }
      z += __shfl_xor(z, 1);
      z += __shfl_xor(z, 2);
      ztail = z * QSC;                 // into exp2 domain
    }

    #pragma unroll
    for (int r = 0; r < 4; ++r) {
      float zt = __shfl(ztail, ((lane >> 4) * 4 + r) * 4);
      float mv = fmaxf(mrun[r], zt);
      float fs = exp2f(mrun[r] - mv);          // mrun=NEGBIG -> 0 (wipes junk)
      float pwgt = exp2f(zt - mv);
      lrun[r] = lrun[r] * fs + pwgt;
      int tr = rows[r];
      int ltr = tr & ~7;
      #pragma unroll
      for (int f = 0; f < 4; ++f) {
        int d = f * 16 + col;
        float v1 = vcum[((size_t)bh * T_ + tr) * HS_ + d];
        float vt = (ltr > 0) ? v1 - vcum[((size_t)bh * T_ + (ltr - 1)) * HS_ + d] : v1;
        O[f][r] = O[f][r] * fs + pwgt * vt;
      }
      mrun[r] = mv;
    }
  }

  if (ngrp == 1) {
    #pragma unroll
    for (int r = 0; r < 4; ++r) {
      float inv = 1.f / lrun[r];
      unsigned short* orow = attnb + (size_t)(b * T_ + rows[r]) * CD + h * HS_;
      #pragma unroll
      for (int f = 0; f < 4; ++f)
        orow[f * 16 + col] = f2bf(O[f][r] * inv);
    }
  } else {
    const int pidx = (((bh << 4) + (tch - 16)) << 1) + grp;
    #pragma unroll
    for (int r = 0; r < 4; ++r) {
      int lrow = w * 16 + (lane >> 4) * 4 + r;
      unsigned short* prow = pO + (size_t)pidx * 4096 + lrow * 64;
      #pragma unroll
      for (int f = 0; f < 4; ++f)
        prow[f * 16 + col] = f2bf(O[f][r]);
      if (col == 0) {
        pm[pidx * 64 + lrow] = mrun[r];
        pl[pidx * 64 + lrow] = lrun[r];
      }
    }
  }
}

// ---------------- K6: combine split partials -> attnb ----------------------
__global__ __launch_bounds__(256) void combine(
    const unsigned short* __restrict__ pO, const float* __restrict__ pm,
    const float* __restrict__ pl, unsigned short* __restrict__ attnb)
{
  int blk = blockIdx.x;             // 512: bh*16 + tc
  int bh = blk >> 4, tc = blk & 15;
  int b = bh >> 4, h = bh & 15;
  int tch = 16 + tc;
  int tid = threadIdx.x;
  int row = tid >> 2;
  int d0  = (tid & 3) * 16;
  int p0 = (((bh << 4) + tc) << 1), p1 = p0 + 1;

  float m0 = pm[p0 * 64 + row], l0 = pl[p0 * 64 + row];
  float m1 = pm[p1 * 64 + row], l1 = pl[p1 * 64 + row];
  float m  = fmaxf(m0, m1);
  float w0 = exp2f(m0 - m), w1 = exp2f(m1 - m);
  float linv = 1.f / (l0 * w0 + l1 * w1);

  const unsigned short* o0 = pO + (size_t)p0 * 4096 + row * 64 + d0;
  const unsigned short* o1 = pO + (size_t)p1 * 4096 + row * 64 + d0;
  unsigned short* orow = attnb + (size_t)(b * T_ + tch * 64 + row) * CD + h * HS_ + d0;
  short8 a0 = *(const short8*)o0, a1 = *(const short8*)o1;
  short8 b0 = *(const short8*)(o0 + 8), b1 = *(const short8*)(o1 + 8);
  #pragma unroll
  for (int jj = 0; jj < 8; ++jj) {
    float v = bf2f((unsigned short)a0[jj]) * w0 + bf2f((unsigned short)a1[jj]) * w1;
    orow[jj] = f2bf(v * linv);
  }
  #pragma unroll
  for (int jj = 0; jj < 8; ++jj) {
    float v = bf2f((unsigned short)b0[jj]) * w0 + bf2f((unsigned short)b1[jj]) * w1;
    orow[8 + jj] = f2bf(v * linv);
  }
}

// --------------------------------------------------------------------------
extern "C" void kernel_launch(void* const* d_in, const int* in_sizes, int n_in,
                              void* d_out, int out_size, void* d_ws, size_t ws_size,
                              hipStream_t stream) {
  const float* x  = (const float*)d_in[0];   // [B,T,C]
  const float* Wa = (const float*)d_in[1];   // [3C,C]
  const float* Wp = (const float*)d_in[2];   // [C,C]
  float* out = (float*)d_out;                // [B,T,C]

  char* ws = (char*)d_ws;
  size_t off = 0;
  auto alloc = [&](size_t bytes) -> char* {
    char* p = ws + off;
    off += (bytes + 255) & ~(size_t)255;
    return p;
  };

  const int M = B_ * T_;                     // 4096
  float* qkv  = (float*)alloc((size_t)M * QKV_LD * 4);            // 50.3 MB
  float* kcum = (float*)alloc((size_t)B_ * NH_ * T_ * HS_ * 4);   // 16.8 MB
  float* vcum = (float*)alloc((size_t)B_ * NH_ * T_ * HS_ * 4);   // 16.8 MB
  float* part = (float*)alloc((size_t)B_ * 128 * 2048 * 4);       // 2 MB
  unsigned short* wph = (unsigned short*)alloc((size_t)CD * CD * 2);

  // fp16 staging aliases: dead before kcum/vcum are first written (cs_final)
  unsigned short* xf    = (unsigned short*)kcum;    // 8.4 MB
  unsigned short* wakvf = (unsigned short*)vcum;    // 4 MB

  // regionA: x_hi/x_lo (live through q-gemm), then set arrays + partials
  char* regionA = alloc((size_t)16777216);
  unsigned short* xh = (unsigned short*)regionA;
  unsigned short* xl = (unsigned short*)(regionA + (size_t)M * CD * 2);
  const size_t SETS_ELEMS = (size_t)B_ * NH_ * NSP * HS_;          // 1M
  unsigned short* Ksh = (unsigned short*)regionA;                  // 2 MB
  unsigned short* Ksl = Ksh + SETS_ELEMS;                          // 2 MB
  unsigned short* Vst = (unsigned short*)(regionA + 2 * SETS_ELEMS * 2);
  int*            r_srt = (int*)(regionA + 3 * SETS_ELEMS * 2);    // @6MB, 2KB
  float*          pm  = (float*)(regionA + 3 * SETS_ELEMS * 2 + 4096);       // 256KB
  float*          pl  = (float*)(regionA + 3 * SETS_ELEMS * 2 + 4096 + 262144);
  unsigned short* pO  = (unsigned short*)(regionA + (size_t)8 * 1048576);    // 8 MB

  // regionB: Waq hi/lo (live through q-gemm), then attn bf16 output
  char* regionB = alloc((size_t)12582912);
  unsigned short* waqh = (unsigned short*)regionB;                 // 2 MB
  unsigned short* waql = (unsigned short*)(regionB + (size_t)CD * CD * 2);
  unsigned short* attnb = (unsigned short*)regionB;

  // K1: fused splits
  split3_kernel<<<dim3(32768), dim3(256), 0, stream>>>(
      x, Wa, Wp, xh, xl, xf, waqh, waql, wakvf, wph);

  // K2a: q = x @ Waq^T  (split-bf16, ~f32 precision; BN=64 -> 512 blocks)
  gemm_bt<1, 64, 0><<<dim3(512), dim3(256), 0, stream>>>(
      xh, xl, waqh, waql, qkv, M, 1024, CD, QKV_LD);

  // K2b: k,v = x @ Wakv^T  (plain fp16)
  gemm_bt<0, 128, 1><<<dim3(512), dim3(256), 0, stream>>>(
      xf, (const unsigned short*)nullptr, wakvf, (const unsigned short*)nullptr,
      qkv + 1024, M, 2048, CD, QKV_LD);

  // K3: phi + cumsums (16-row segments -> 512 blocks each)
  cs_part<<<dim3(B_ * 128 * 2), dim3(256), 0, stream>>>(qkv, part);
  cs_final<<<dim3(B_ * 128 * 2), dim3(256), 0, stream>>>(qkv, part, kcum, vcum);

  // K4: sorted set aggregates + fused V transpose
  build_sets2<<<dim3(B_ * NH_ * 8), dim3(256), 0, stream>>>(
      kcum, vcum, Ksh, Ksl, Vst, r_srt);

  // K5: MFMA attention (set-split 1536 blocks, 26.6KB LDS -> 6/CU resident)
  attn_mfma<<<dim3(1536), dim3(256), 0, stream>>>(
      qkv, kcum, vcum, Ksh, Ksl, Vst, r_srt, attnb, pO, pm, pl);

  // K6: combine split partials (rows t >= 1024)
  combine<<<dim3(512), dim3(256), 0, stream>>>(pO, pm, pl, attnb);

  // K7: out = attn @ Wp^T  (BN=64 -> 512 blocks, 2/CU)
  gemm_bt<0, 64, 0><<<dim3(512), dim3(256), 0, stream>>>(
      attnb, (const unsigned short*)nullptr, wph, (const unsigned short*)nullptr,
      out, M, 1024, CD, CD);
}

// Round 20
// 185.577 us; speedup vs baseline: 1.0224x; 1.0224x over previous
//
#include <hip/hip_runtime.h>
#include <hip/hip_bf16.h>
#include <stdint.h>

// Problem constants (B,T,C,NH,LEVEL) = (2,2048,1024,16,3)
#define B_    2
#define T_    2048
#define CD    1024
#define NH_   16
#define HS_   64
#define NSETS 511        // sum_{l=3..11} 2048>>l
#define NSP   512        // padded
#define QKV_LD 3072
#define NEGBIG (-3.4e38f)
#define QSC   (0.125f * 1.44269504088896f)   // scale * log2(e): exp2-domain softmax

typedef __attribute__((ext_vector_type(8))) short  short8;
typedef __attribute__((ext_vector_type(4))) float  f32x4;
typedef _Float16 half8v __attribute__((ext_vector_type(8)));

__device__ __forceinline__ unsigned short f2bf(float f) {
  unsigned u = __float_as_uint(f);
  unsigned r = 0x7FFFu + ((u >> 16) & 1u);   // round-to-nearest-even
  return (unsigned short)((u + r) >> 16);
}
__device__ __forceinline__ float bf2f(unsigned short h) {
  return __uint_as_float(((unsigned)h) << 16);
}
__device__ __forceinline__ unsigned short f2h(float v) {
  _Float16 h = (_Float16)v;                  // RTN, single v_cvt_f16_f32
  return __builtin_bit_cast(unsigned short, h);
}
__device__ __forceinline__ float elu1(float x) {  // elu(x)+1
  return x > 0.f ? x + 1.f : __expf(x);
}
__device__ __forceinline__ void gload16(const unsigned short* g, short* l) {
  __builtin_amdgcn_global_load_lds(
      (const __attribute__((address_space(1))) unsigned int*)g,
      (__attribute__((address_space(3))) unsigned int*)l, 16, 0, 0);
}

// ---------------- K1: fused splits -----------------------------------------
__global__ __launch_bounds__(256) void split3_kernel(
    const float* __restrict__ x, const float* __restrict__ Wa,
    const float* __restrict__ Wp,
    unsigned short* __restrict__ xh, unsigned short* __restrict__ xl,
    unsigned short* __restrict__ xf,
    unsigned short* __restrict__ waqh, unsigned short* __restrict__ waql,
    unsigned short* __restrict__ wakvf, unsigned short* __restrict__ wph) {
  int bid = blockIdx.x;
  int t = threadIdx.x;
  if (bid < 16384) {                     // x: 4096x1024
    int i = bid * 256 + t;
    float v = x[i];
    unsigned short h = f2bf(v);
    xh[i] = h;
    xl[i] = f2bf(v - bf2f(h));
    xf[i] = f2h(v);
  } else if (bid < 20480) {              // Wa rows 0..1023 (q)
    int i = (bid - 16384) * 256 + t;
    float v = Wa[i];
    unsigned short h = f2bf(v);
    waqh[i] = h;
    waql[i] = f2bf(v - bf2f(h));
  } else if (bid < 28672) {              // Wa rows 1024..3071 (k,v)
    int i = (bid - 20480) * 256 + t;
    wakvf[i] = f2h(Wa[1048576 + i]);
  } else {                               // Wp
    int i = (bid - 28672) * 256 + t;
    wph[i] = f2bf(Wp[i]);
  }
}

// ---------------- GEMM body: C[128 x BN tile] = A*B^T (MFMA) ---------------
template<int SPLIT, int BN, int F16>
__device__ __forceinline__ void gemm_body(
    short* lds,
    const unsigned short* __restrict__ Ah, const unsigned short* __restrict__ Al,
    const unsigned short* __restrict__ Bh, const unsigned short* __restrict__ Bl,
    float* __restrict__ Cmat, int K, int ldc, int row0, int col0)
{
  constexpr int NB   = BN / 16;
  constexpr int ALD  = 8 * (1 + SPLIT);
  constexpr int TL   = ALD + NB * (1 + SPLIT);
  constexpr int PW   = TL / 4;
  constexpr int ASH  = (1 + SPLIT) * 4096;
  constexpr int ABYT = ASH * 2;
  constexpr int NC   = BN / 32;

  const int tid  = threadIdx.x;
  const int lane = tid & 63;
  const int w    = tid >> 6;
  const int wr   = w >> 1, wc = w & 1;

  f32x4 acc[4][NC];
  #pragma unroll
  for (int a = 0; a < 4; ++a)
    #pragma unroll
    for (int b = 0; b < NC; ++b)
      acc[a][b] = (f32x4){0.f, 0.f, 0.f, 0.f};

  const int rlane = lane & 15;
  const int kgrp  = lane >> 4;
  const int rsw   = (kgrp ^ (rlane & 3) ^ ((rlane >> 2) & 3)) << 4;

  const int slr = lane >> 2;
  const int sch = (lane & 3) ^ (slr & 3) ^ ((slr >> 2) & 3);

  for (int kt = 0; kt < K; kt += 32) {
    __syncthreads();
    #pragma unroll
    for (int li = 0; li < PW; ++li) {
      int L = w * PW + li;
      const unsigned short* src; int dsts; size_t rowb;
      if (L < 8)                { src = Ah; rowb = (size_t)row0 + L * 16;       dsts = L * 512; }
      else if (SPLIT && L < 16) { src = Al; rowb = (size_t)row0 + (L - 8) * 16; dsts = 4096 + (L - 8) * 512; }
      else {
        int Lb = L - ALD;
        if (!SPLIT || Lb < NB) { src = Bh; rowb = (size_t)col0 + Lb * 16;        dsts = ASH + Lb * 512; }
        else                   { src = Bl; rowb = (size_t)col0 + (Lb - NB) * 16; dsts = ASH + BN * 32 + (Lb - NB) * 512; }
      }
      gload16(src + (rowb + slr) * K + kt + (sch << 3), lds + dsts + lane * 8);
    }
    __syncthreads();

    short8 aH[4], bH[NC], aL[4], bL[NC];
    #pragma unroll
    for (int m = 0; m < 4; ++m) {
      int r = wr * 64 + m * 16 + rlane;
      aH[m] = *(const short8*)((const char*)lds + r * 64 + rsw);
      if (SPLIT) aL[m] = *(const short8*)((const char*)lds + 8192 + r * 64 + rsw);
    }
    #pragma unroll
    for (int n = 0; n < NC; ++n) {
      int c = wc * (BN / 2) + n * 16 + rlane;
      bH[n] = *(const short8*)((const char*)lds + ABYT + c * 64 + rsw);
      if (SPLIT) bL[n] = *(const short8*)((const char*)lds + ABYT + BN * 64 + c * 64 + rsw);
    }
    #pragma unroll
    for (int mm = 0; mm < 4; ++mm)
      #pragma unroll
      for (int nn = 0; nn < NC; ++nn) {
        if (F16) {
          acc[mm][nn] = __builtin_amdgcn_mfma_f32_16x16x32_f16(
              __builtin_bit_cast(half8v, aH[mm]), __builtin_bit_cast(half8v, bH[nn]),
              acc[mm][nn], 0, 0, 0);
        } else {
          acc[mm][nn] = __builtin_amdgcn_mfma_f32_16x16x32_bf16(aH[mm], bH[nn], acc[mm][nn], 0, 0, 0);
          if (SPLIT) {
            acc[mm][nn] = __builtin_amdgcn_mfma_f32_16x16x32_bf16(aH[mm], bL[nn], acc[mm][nn], 0, 0, 0);
            acc[mm][nn] = __builtin_amdgcn_mfma_f32_16x16x32_bf16(aL[mm], bH[nn], acc[mm][nn], 0, 0, 0);
          }
        }
      }
  }

  const int rl = (lane >> 4) * 4;
  const int cl = lane & 15;
  #pragma unroll
  for (int mm = 0; mm < 4; ++mm)
    #pragma unroll
    for (int nn = 0; nn < NC; ++nn)
      #pragma unroll
      for (int r = 0; r < 4; ++r) {
        int row = row0 + wr * 64 + mm * 16 + rl + r;
        int col = col0 + wc * (BN / 2) + nn * 16 + cl;
        Cmat[(size_t)row * ldc + col] = acc[mm][nn][r];
      }
}

// ---------------- K2/K7: standalone GEMM with XCD swizzle ------------------
template<int SPLIT, int BN, int F16>
__global__ __launch_bounds__(256) void gemm_bt(
    const unsigned short* __restrict__ Ah, const unsigned short* __restrict__ Al,
    const unsigned short* __restrict__ Bh, const unsigned short* __restrict__ Bl,
    float* __restrict__ Cmat, int M, int N, int K, int ldc)
{
  __shared__ short lds[(1 + SPLIT) * 4096 + (1 + SPLIT) * BN * 32];
  const int nwg = gridDim.x;
  const int cpx = nwg >> 3;
  const int bid = blockIdx.x;
  const int swb = (bid & 7) * cpx + (bid >> 3);
  const int nbx = N / BN;
  const int bx = swb % nbx;
  const int by = swb / nbx;
  gemm_body<SPLIT, BN, F16>(lds, Ah, Al, Bh, Bl, Cmat, K, ldc, by * 128, bx * BN);
}

// ---------------- K3a: per-seg partial sums (16-row segments) --------------
__global__ __launch_bounds__(256) void cs_part(const float* __restrict__ qkv,
                                               float* __restrict__ part) {
  int blk = blockIdx.x;                 // B*128*2 = 512
  int q   = blk & 1;
  int seg = (blk >> 1) & 127;
  int b   = blk >> 8;
  int c   = threadIdx.x * 4;            // 0..1023
  const float* src = qkv + (size_t)(b * T_ + seg * 16) * QKV_LD + CD + q * CD + c;
  float4 s = {0.f, 0.f, 0.f, 0.f};
  #pragma unroll 4
  for (int j = 0; j < 16; ++j) {
    float4 v = *(const float4*)(src + (size_t)j * QKV_LD);
    if (q == 0) {
      s.x += elu1(v.x); s.y += elu1(v.y); s.z += elu1(v.z); s.w += elu1(v.w);
    } else {
      s.x += v.x; s.y += v.y; s.z += v.z; s.w += v.w;
    }
  }
  *(float4*)(part + ((size_t)(b * 128 + seg) * 2048) + q * 1024 + c) = s;
}

// ---------------- K3b: final walk with self-prefix -> kcum / vcum ---------
__global__ __launch_bounds__(256) void cs_final(const float* __restrict__ qkv,
                                                const float* __restrict__ part,
                                                float* __restrict__ kcum,
                                                float* __restrict__ vcum) {
  int blk = blockIdx.x;                 // 512
  int q   = blk & 1;
  int seg = (blk >> 1) & 127;
  int b   = blk >> 8;
  int c   = threadIdx.x * 4;
  int h   = c >> 6, d = c & 63;
  float4 s = {0.f, 0.f, 0.f, 0.f};
  const float* pb = part + (size_t)(b * 128) * 2048 + q * 1024 + c;
  #pragma unroll 8
  for (int ss = 0; ss < seg; ++ss) {
    float4 p = *(const float4*)(pb + (size_t)ss * 2048);
    s.x += p.x; s.y += p.y; s.z += p.z; s.w += p.w;
  }
  const float* src = qkv + (size_t)(b * T_ + seg * 16) * QKV_LD + CD + q * CD + c;
  float* dst = (q == 0 ? kcum : vcum) + ((size_t)(b * NH_ + h) * T_ + seg * 16) * HS_ + d;
  #pragma unroll 4
  for (int j = 0; j < 16; ++j) {
    float4 v = *(const float4*)(src + (size_t)j * QKV_LD);
    if (q == 0) {
      s.x += elu1(v.x); s.y += elu1(v.y); s.z += elu1(v.z); s.w += elu1(v.w);
    } else {
      s.x += v.x; s.y += v.y; s.z += v.z; s.w += v.w;
    }
    *(float4*)(dst + (size_t)j * HS_) = s;
  }
}

// ---------------- K4: sorted set aggregates + fused V transpose ------------
// K split-bf16 (hi/lo); Vst stored FP16 (better mantissa, 1-op convert).
__global__ __launch_bounds__(256) void build_sets2(
    const float* __restrict__ kcum, const float* __restrict__ vcum,
    unsigned short* __restrict__ Ksh, unsigned short* __restrict__ Ksl,
    unsigned short* __restrict__ Vst, int* __restrict__ r_srt)
{
  __shared__ int   lr[64], lli[64];
  __shared__ float vt[64][65];
  const int bh = blockIdx.x >> 3;
  const int s0 = (blockIdx.x & 7) * 64;
  const int tid = threadIdx.x;

  for (int s = tid; s < NSP; s += 256) {
    int r, li, rank;
    if (s == NSETS) { r = 0x7fffffff; li = 0; rank = NSETS; }
    else {
      int lvl = 3, base = 0;
      while (s >= base + (T_ >> lvl)) { base += T_ >> lvl; ++lvl; }
      int i = s - base;
      int m = (i + 1) << lvl;
      r = m - 1; li = i << lvl;
      rank = lvl - 3;
      #pragma unroll
      for (int j = 3; j <= 11; ++j) rank += (m - 8) >> j;
    }
    if (rank >= s0 && rank < s0 + 64) {
      lr[rank - s0]  = r;
      lli[rank - s0] = li;
      if (bh == 0) r_srt[rank] = r;
    }
  }
  __syncthreads();

  const int sl = tid >> 2;          // local rank
  const int dq = (tid & 3) * 16;
  const int r  = lr[sl], li = lli[sl];
  const size_t orow = ((size_t)(bh << 9) + s0 + sl) * HS_ + dq;
  short8 kh0, kh1, kl0, kl1;
  if (r == 0x7fffffff) {
    #pragma unroll
    for (int j = 0; j < 8; ++j) { kh0[j]=0; kh1[j]=0; kl0[j]=0; kl1[j]=0; }
    #pragma unroll
    for (int j = 0; j < 16; ++j) vt[sl][dq + j] = 0.f;
  } else {
    const float* kr0 = kcum + ((size_t)bh * T_ + r) * HS_ + dq;
    const float* vr0 = vcum + ((size_t)bh * T_ + r) * HS_ + dq;
    const float* kr1 = kcum + ((size_t)bh * T_ + (li - 1)) * HS_ + dq;
    const float* vr1 = vcum + ((size_t)bh * T_ + (li - 1)) * HS_ + dq;
    #pragma unroll
    for (int g = 0; g < 4; ++g) {
      float4 kv = *(const float4*)(kr0 + g * 4);
      float4 vv = *(const float4*)(vr0 + g * 4);
      if (li > 0) {
        float4 k1 = *(const float4*)(kr1 + g * 4);
        float4 v1 = *(const float4*)(vr1 + g * 4);
        kv.x -= k1.x; kv.y -= k1.y; kv.z -= k1.z; kv.w -= k1.w;
        vv.x -= v1.x; vv.y -= v1.y; vv.z -= v1.z; vv.w -= v1.w;
      }
      float ka[4] = {kv.x, kv.y, kv.z, kv.w};
      float va[4] = {vv.x, vv.y, vv.z, vv.w};
      #pragma unroll
      for (int j = 0; j < 4; ++j) {
        int e = g * 4 + j;
        unsigned short h = f2bf(ka[j]);
        unsigned short l = f2bf(ka[j] - bf2f(h));
        if (e < 8) { kh0[e] = (short)h; kl0[e] = (short)l; }
        else       { kh1[e - 8] = (short)h; kl1[e - 8] = (short)l; }
        vt[sl][dq + e] = va[j];
      }
    }
  }
  *(short8*)(Ksh + orow)     = kh0;
  *(short8*)(Ksh + orow + 8) = kh1;
  *(short8*)(Ksl + orow)     = kl0;
  *(short8*)(Ksl + orow + 8) = kl1;
  __syncthreads();

  const int d  = tid >> 2;
  const int sq = (tid & 3) * 16;
  short8 a, b2;
  #pragma unroll
  for (int j = 0; j < 8; ++j) {
    a[j]  = (short)f2h(vt[sq + j][d]);
    b2[j] = (short)f2h(vt[sq + 8 + j][d]);
  }
  unsigned short* dst = Vst + ((size_t)(bh << 6) + d) * NSP + s0 + sq;
  *(short8*)dst = a;
  *(short8*)(dst + 8) = b2;
}

// ---------------- K5: MFMA flash attention, 64 q-rows per block ------------
// R18 geometry: 1024 blocks x 256 thr, balanced XCD map, P aliases the dead
// Ksh LDS region (26.6KB). P + Vst in FP16: 1-op convert (vs 3-op bf16 RTN)
// and better mantissa; PV MFMA = mfma_f32_16x16x32_f16.
__global__ __launch_bounds__(256) void attn_mfma(
    const float* __restrict__ qkv, const float* __restrict__ kcum,
    const float* __restrict__ vcum,
    const unsigned short* __restrict__ Ksh, const unsigned short* __restrict__ Ksl,
    const unsigned short* __restrict__ Vst, const int* __restrict__ r_srt,
    unsigned short* __restrict__ attnb)
{
  __shared__ short KV[3 * 4096];        // 24KB; Ksh region doubles as P buffer
  __shared__ int   rs_lds[NSP];         // 2KB

  const int blk = blockIdx.x;           // 1024
  const int xcd = blk & 7;
  const int j   = blk >> 3;             // 0..127
  const int bh  = xcd * 4 + (j >> 5);
  const int tch = (j + ((j >> 5) << 3)) & 31;
  const int b = bh >> 4, h = bh & 15;
  const int t0 = tch * 64;
  const int tid = threadIdx.x;
  const int lane = tid & 63;
  const int w = tid >> 6;
  const int col = lane & 15;
  const int kgrp = (lane >> 4) * 8;

  const int srow = lane >> 3;
  const int scsw = ((lane & 7) ^ srow) * 8;

  auto stage_tile = [&](int s0) {
    #pragma unroll
    for (int L = w * 6; L < w * 6 + 6; ++L) {
      int a = L >> 3, i = L & 7;
      const unsigned short* src;
      if (a == 0)      src = Ksh + ((size_t)(bh << 9) + s0 + i * 8 + srow) * 64 + scsw;
      else if (a == 1) src = Ksl + ((size_t)(bh << 9) + s0 + i * 8 + srow) * 64 + scsw;
      else             src = Vst + ((size_t)(bh << 6) + i * 8 + srow) * NSP + s0 + scsw;
      gload16(src, KV + a * 4096 + i * 512 + lane * 8);
    }
  };

  // ---- Q fragments: global -> pre-scaled split bf16 hi/lo in registers ----
  short8 qh[2], ql[2];
  {
    int qrow = t0 + w * 16 + col;
    const float* qr = qkv + (size_t)(b * T_ + qrow) * QKV_LD + h * HS_;
    #pragma unroll
    for (int ks = 0; ks < 2; ++ks) {
      float4 v0 = *(const float4*)(qr + kgrp + ks * 32);
      float4 v1 = *(const float4*)(qr + kgrp + ks * 32 + 4);
      float vv[8] = {v0.x, v0.y, v0.z, v0.w, v1.x, v1.y, v1.z, v1.w};
      #pragma unroll
      for (int jj = 0; jj < 8; ++jj) {
        float sv = vv[jj] * QSC;
        unsigned short hi = f2bf(sv);
        qh[ks][jj] = (short)hi;
        ql[ks][jj] = (short)f2bf(sv - bf2f(hi));
      }
    }
  }
  for (int s = tid; s < NSP; s += 256) rs_lds[s] = r_srt[s];

  int rows[4];
  #pragma unroll
  for (int r = 0; r < 4; ++r) rows[r] = t0 + w * 16 + (lane >> 4) * 4 + r;

  f32x4 O[4];
  float mrun[4], lsum[4];
  #pragma unroll
  for (int f = 0; f < 4; ++f) {
    O[f] = (f32x4){0.f, 0.f, 0.f, 0.f};
    mrun[f] = NEGBIG; lsum[f] = 0.f;
  }

  int nmax = 0;
  #pragma unroll
  for (int jj = 3; jj <= 11; ++jj) nmax += (t0 + 64) >> jj;
  const int ntiles = (nmax + 63) >> 6;

  for (int tile = 0; tile < ntiles; ++tile) {
    const int s0 = tile * 64;
    stage_tile(s0);
    __syncthreads();     // drains gload vmcnt(0); covers Q/rs phase on tile 0

    const char* kc = (const char*)KV;
    f32x4 S[4];
    #pragma unroll
    for (int f = 0; f < 4; ++f) S[f] = (f32x4){0.f, 0.f, 0.f, 0.f};

    __builtin_amdgcn_s_setprio(1);
    #pragma unroll
    for (int ks = 0; ks < 2; ++ks) {
      int chnk = (lane >> 4) + ks * 4;
      #pragma unroll
      for (int f = 0; f < 4; ++f) {
        int so = f * 16 + col;
        int kb = so * 128 + ((chnk ^ (so & 7)) << 4);
        short8 bHv = *(const short8*)(kc + kb);
        short8 bLv = *(const short8*)(kc + 8192 + kb);
        S[f] = __builtin_amdgcn_mfma_f32_16x16x32_bf16(qh[ks], bHv, S[f], 0, 0, 0);
        S[f] = __builtin_amdgcn_mfma_f32_16x16x32_bf16(qh[ks], bLv, S[f], 0, 0, 0);
        S[f] = __builtin_amdgcn_mfma_f32_16x16x32_bf16(ql[ks], bHv, S[f], 0, 0, 0);
      }
    }
    __builtin_amdgcn_s_setprio(0);

    int rsv[4];
    #pragma unroll
    for (int f = 0; f < 4; ++f) rsv[f] = rs_lds[s0 + f * 16 + col];

    // logits already in exp2 domain; mask to NEGBIG (exp2 underflows -> 0)
    float zv[4][4];
    #pragma unroll
    for (int f = 0; f < 4; ++f)
      #pragma unroll
      for (int r = 0; r < 4; ++r)
        zv[f][r] = (rsv[f] > rows[r]) ? NEGBIG : S[f][r];

    float mx[4];
    #pragma unroll
    for (int r = 0; r < 4; ++r)
      mx[r] = fmaxf(fmaxf(zv[0][r], zv[1][r]), fmaxf(zv[2][r], zv[3][r]));
    int pred = (mx[0] <= mrun[0] + 11.5f) & (mx[1] <= mrun[1] + 11.5f) &
               (mx[2] <= mrun[2] + 11.5f) & (mx[3] <= mrun[3] + 11.5f);
    if (!__all(pred)) {
      #pragma unroll
      for (int r = 0; r < 4; ++r) {
        float mt = mx[r];
        mt = fmaxf(mt, __shfl_xor(mt, 1));
        mt = fmaxf(mt, __shfl_xor(mt, 2));
        mt = fmaxf(mt, __shfl_xor(mt, 4));
        mt = fmaxf(mt, __shfl_xor(mt, 8));
        float mv = fmaxf(mrun[r], mt);
        float fs = exp2f(mrun[r] - mv);
        lsum[r] *= fs;
        #pragma unroll
        for (int f = 0; f < 4; ++f) O[f][r] *= fs;
        mrun[r] = mv;
      }
    }

    __syncthreads();     // all waves done reading Ksh/Ksl; P may now overwrite

    // ---- P -> fp16 into the (dead) Ksh region, wave-private 2KB slice ----
    char* pw = (char*)KV + w * 2048;
    #pragma unroll
    for (int r = 0; r < 4; ++r) {
      int rowr = (lane >> 4) * 4 + r;
      int rswz = (rowr & 7) << 4;
      #pragma unroll
      for (int f = 0; f < 4; ++f) {
        // masked entries: exp2(NEGBIG - m) == 0. Rows with mrun==NEGBIG
        // (t<7) accumulate p==1 junk that the tail rescale fs=0 wipes.
        float p = exp2f(zv[f][r] - mrun[r]);
        lsum[r] += p;
        int addr = (rowr * 128 + (f * 16 + col) * 2) ^ rswz;
        *(unsigned short*)(pw + addr) = f2h(p);
      }
    }

    __builtin_amdgcn_s_setprio(1);
    #pragma unroll
    for (int ks = 0; ks < 2; ++ks) {
      int chnk = (lane >> 4) + ks * 4;
      int pbyte = (col * 128 + (kgrp + ks * 32) * 2) ^ ((col & 7) << 4);
      short8 pa = *(const short8*)(pw + pbyte);
      #pragma unroll
      for (int f = 0; f < 4; ++f) {
        int dr = f * 16 + col;
        short8 bv = *(const short8*)(kc + 16384 + dr * 128 + ((chnk ^ (dr & 7)) << 4));
        O[f] = __builtin_amdgcn_mfma_f32_16x16x32_f16(
            __builtin_bit_cast(half8v, pa), __builtin_bit_cast(half8v, bv),
            O[f], 0, 0, 0);
      }
    }
    __builtin_amdgcn_s_setprio(0);

    __syncthreads();     // all waves done reading KV/P before next stage
  }

  float lrun[4];
  #pragma unroll
  for (int r = 0; r < 4; ++r) {
    float l = lsum[r];
    l += __shfl_xor(l, 1);
    l += __shfl_xor(l, 2);
    l += __shfl_xor(l, 4);
    l += __shfl_xor(l, 8);
    lrun[r] = l;
  }

  // ---- tail term: interval [t&~7, t] with q_phi, per-row VALU ----
  float ztail;
  {
    int trow = lane >> 2;
    int t = t0 + w * 16 + trow;
    int d0 = (lane & 3) * 16;
    const float* qr = qkv + (size_t)(b * T_ + t) * QKV_LD + h * HS_ + d0;
    float qv[16];
    #pragma unroll
    for (int jj = 0; jj < 4; ++jj) {
      float4 v = *(const float4*)(qr + jj * 4);
      qv[jj*4+0] = v.x; qv[jj*4+1] = v.y; qv[jj*4+2] = v.z; qv[jj*4+3] = v.w;
    }
    int lt = t & ~7;
    const float* kc1 = kcum + ((size_t)bh * T_ + t) * HS_ + d0;
    float kt[16];
    if (lt > 0) {
      const float* kc0 = kcum + ((size_t)bh * T_ + (lt - 1)) * HS_ + d0;
      #pragma unroll
      for (int jj = 0; jj < 16; ++jj) kt[jj] = kc1[jj] - kc0[jj];
    } else {
      #pragma unroll
      for (int jj = 0; jj < 16; ++jj) kt[jj] = kc1[jj];
    }
    float z = 0.f;
    #pragma unroll
    for (int jj = 0; jj < 16; ++jj) {
      float qp = qv[jj] > 0.f ? qv[jj] + 1.f : __expf(qv[jj]);
      z += qp * kt[jj];
    }
    z += __shfl_xor(z, 1);
    z += __shfl_xor(z, 2);
    ztail = z * QSC;                   // into exp2 domain
  }

  #pragma unroll
  for (int r = 0; r < 4; ++r) {
    float zt = __shfl(ztail, ((lane >> 4) * 4 + r) * 4);
    float mv = fmaxf(mrun[r], zt);
    float fs = exp2f(mrun[r] - mv);            // mrun=NEGBIG -> 0 (wipes junk)
    float pwgt = exp2f(zt - mv);
    lrun[r] = lrun[r] * fs + pwgt;
    int tr = rows[r];
    int ltr = tr & ~7;
    #pragma unroll
    for (int f = 0; f < 4; ++f) {
      int d = f * 16 + col;
      float v1 = vcum[((size_t)bh * T_ + tr) * HS_ + d];
      float vt = (ltr > 0) ? v1 - vcum[((size_t)bh * T_ + (ltr - 1)) * HS_ + d] : v1;
      O[f][r] = O[f][r] * fs + pwgt * vt;
    }
  }

  #pragma unroll
  for (int r = 0; r < 4; ++r) {
    float inv = 1.f / lrun[r];
    unsigned short* orow = attnb + (size_t)(b * T_ + rows[r]) * CD + h * HS_;
    #pragma unroll
    for (int f = 0; f < 4; ++f)
      orow[f * 16 + col] = f2bf(O[f][r] * inv);
  }
}

// --------------------------------------------------------------------------
extern "C" void kernel_launch(void* const* d_in, const int* in_sizes, int n_in,
                              void* d_out, int out_size, void* d_ws, size_t ws_size,
                              hipStream_t stream) {
  const float* x  = (const float*)d_in[0];   // [B,T,C]
  const float* Wa = (const float*)d_in[1];   // [3C,C]
  const float* Wp = (const float*)d_in[2];   // [C,C]
  float* out = (float*)d_out;                // [B,T,C]

  char* ws = (char*)d_ws;
  size_t off = 0;
  auto alloc = [&](size_t bytes) -> char* {
    char* p = ws + off;
    off += (bytes + 255) & ~(size_t)255;
    return p;
  };

  const int M = B_ * T_;                     // 4096
  float* qkv  = (float*)alloc((size_t)M * QKV_LD * 4);            // 50.3 MB
  float* kcum = (float*)alloc((size_t)B_ * NH_ * T_ * HS_ * 4);   // 16.8 MB
  float* vcum = (float*)alloc((size_t)B_ * NH_ * T_ * HS_ * 4);   // 16.8 MB
  float* part = (float*)alloc((size_t)B_ * 128 * 2048 * 4);       // 2 MB
  unsigned short* wph = (unsigned short*)alloc((size_t)CD * CD * 2);

  // fp16 staging aliases: dead before kcum/vcum are first written (cs_final)
  unsigned short* xf    = (unsigned short*)kcum;    // 8.4 MB
  unsigned short* wakvf = (unsigned short*)vcum;    // 4 MB

  // regionA: x_hi/x_lo (live through q-gemm), then sorted set arrays
  char* regionA = alloc((size_t)16777216);
  unsigned short* xh = (unsigned short*)regionA;
  unsigned short* xl = (unsigned short*)(regionA + (size_t)M * CD * 2);
  const size_t SETS_ELEMS = (size_t)B_ * NH_ * NSP * HS_;
  unsigned short* Ksh = (unsigned short*)regionA;                  // 2 MB
  unsigned short* Ksl = Ksh + SETS_ELEMS;                          // 2 MB
  unsigned short* Vst = (unsigned short*)(regionA + 2 * SETS_ELEMS * 2);
  int*            r_srt = (int*)(regionA + 3 * SETS_ELEMS * 2);

  // regionB: Waq hi/lo (live through q-gemm), then attn bf16 output
  char* regionB = alloc((size_t)12582912);
  unsigned short* waqh = (unsigned short*)regionB;                 // 2 MB
  unsigned short* waql = (unsigned short*)(regionB + (size_t)CD * CD * 2);
  unsigned short* attnb = (unsigned short*)regionB;

  // K1: fused splits
  split3_kernel<<<dim3(32768), dim3(256), 0, stream>>>(
      x, Wa, Wp, xh, xl, xf, waqh, waql, wakvf, wph);

  // K2a: q = x @ Waq^T  (split-bf16, ~f32 precision; BN=64 -> 512 blocks)
  gemm_bt<1, 64, 0><<<dim3(512), dim3(256), 0, stream>>>(
      xh, xl, waqh, waql, qkv, M, 1024, CD, QKV_LD);

  // K2b: k,v = x @ Wakv^T  (plain fp16)
  gemm_bt<0, 128, 1><<<dim3(512), dim3(256), 0, stream>>>(
      xf, (const unsigned short*)nullptr, wakvf, (const unsigned short*)nullptr,
      qkv + 1024, M, 2048, CD, QKV_LD);

  // K3: phi + cumsums (16-row segments -> 512 blocks each)
  cs_part<<<dim3(B_ * 128 * 2), dim3(256), 0, stream>>>(qkv, part);
  cs_final<<<dim3(B_ * 128 * 2), dim3(256), 0, stream>>>(qkv, part, kcum, vcum);

  // K4: sorted set aggregates + fused V transpose (Vst fp16)
  build_sets2<<<dim3(B_ * NH_ * 8), dim3(256), 0, stream>>>(
      kcum, vcum, Ksh, Ksl, Vst, r_srt);

  // K5: MFMA attention (P/Vst fp16; P aliased into dead Ksh LDS)
  attn_mfma<<<dim3(1024), dim3(256), 0, stream>>>(
      qkv, kcum, vcum, Ksh, Ksl, Vst, r_srt, attnb);

  // K7: out = attn @ Wp^T  (BN=64 -> 512 blocks, 2/CU)
  gemm_bt<0, 64, 0><<<dim3(512), dim3(256), 0, stream>>>(
      attnb, (const unsigned short*)nullptr, wph, (const unsigned short*)nullptr,
      out, M, 1024, CD, CD);
}